// Round 1
// baseline (224.152 us; speedup 1.0000x reference)
//
#include <hip/hip_runtime.h>
#include <hip/hip_bf16.h>

// Problem constants (fixed by reference setup)
#define B 32
#define HW 16384           // h*w = 128*128 per (b,c) row
#define NROW 128
#define POOL 8
#define GTW 1024           // W = 128*8
#define TOTAL (B * HW)     // 524288 elements
#define LOSS_BLOCKS 1024

// -------------------- K1: 8x8 block-sum pooling --------------------
// gt: [B][1024][1024] f32 -> dg: [B][128][128] f32
__global__ __launch_bounds__(256) void pool_kernel(const float* __restrict__ gt,
                                                   float* __restrict__ dg) {
    int out = blockIdx.x * 256 + threadIdx.x;     // 0 .. TOTAL-1
    int b   = out >> 14;                          // /16384
    int rem = out & (HW - 1);
    int oi  = rem >> 7;                           // output row
    int oj  = rem & (NROW - 1);                   // output col
    const float* base = gt + ((size_t)b << 20) + (size_t)(oi * POOL) * GTW + oj * POOL;
    float s = 0.f;
#pragma unroll
    for (int r = 0; r < POOL; ++r) {
        const float4* p = reinterpret_cast<const float4*>(base + (size_t)r * GTW);
        float4 a = p[0];
        float4 c = p[1];
        s += a.x + a.y + a.z + a.w + c.x + c.y + c.z + c.w;
    }
    dg[out] = s;
}

// -------------------- K2: exact k-th largest per row via bit bisection ----
// blockIdx.x = row*2 + which  (which: 0 = err vs dmap_conv, 1 = err vs dmap_tran)
// thr layout: thr[which*32 + b]
__global__ __launch_bounds__(256) void select_kernel(const float* __restrict__ dc_all,
                                                     const float* __restrict__ dt_all,
                                                     const float* __restrict__ dg_all,
                                                     const int* __restrict__ process,
                                                     float* __restrict__ thr_out) {
    int b     = blockIdx.x >> 1;
    int which = blockIdx.x & 1;
    const float* dm = (which ? dt_all : dc_all) + (size_t)b * HW;
    const float* dg = dg_all + (size_t)b * HW;

    int p = process[0];
    int num = (int)(16384.0 * (0.1 * (double)p));   // matches Python int() truncation
    if (num > HW) num = HW;

    int t = threadIdx.x;

    if (num < 1) {
        if (t == 0) thr_out[which * B + b] = __uint_as_float(0x7F800000u); // +inf -> select nothing
        return;
    }

    // Hold the row's 16384 err values in registers: 64 per thread
    float e[64];
#pragma unroll
    for (int i = 0; i < 64; ++i) {
        int idx = i * 256 + t;                      // coalesced
        e[i] = fabsf(dg[idx] - dm[idx]);
    }

    __shared__ unsigned s_lo, s_hi;
    __shared__ int s_cnt[4];
    if (t == 0) { s_lo = 0u; s_hi = 0x7F800000u; }  // cnt(>=0)=16384>=num ; cnt(>=inf)=0<num
    __syncthreads();

    // invariant: cnt(err >= f(s_lo)) >= num, cnt(err >= f(s_hi)) < num
    while (true) {
        unsigned lo = s_lo, hi = s_hi;
        if (hi - lo <= 1u) break;
        unsigned mid = lo + ((hi - lo) >> 1);
        float fmid = __uint_as_float(mid);
        int c = 0;
#pragma unroll
        for (int i = 0; i < 64; ++i) c += (e[i] >= fmid) ? 1 : 0;
#pragma unroll
        for (int off = 32; off > 0; off >>= 1) c += __shfl_down(c, off, 64);
        if ((t & 63) == 0) s_cnt[t >> 6] = c;
        __syncthreads();
        if (t == 0) {
            int tot = s_cnt[0] + s_cnt[1] + s_cnt[2] + s_cnt[3];
            if (tot >= num) s_lo = mid; else s_hi = mid;
        }
        __syncthreads();
    }

    if (t == 0) thr_out[which * B + b] = __uint_as_float(s_lo); // exact num-th largest value
}

// -------------------- K3: masked MSE contributions -> per-block f64 partials
__global__ __launch_bounds__(256) void loss_kernel(const float* __restrict__ dc_all,
                                                   const float* __restrict__ dt_all,
                                                   const float* __restrict__ dg_all,
                                                   const int* __restrict__ process,
                                                   const float* __restrict__ thr,
                                                   double* __restrict__ part) {
    int p = process[0];
    int num = (int)(16384.0 * (0.1 * (double)p));
    float w = (float)(1.0 * (double)p);             // MAX_WEIGHT_RATIO * process

    double acc = 0.0;
    for (int idx = blockIdx.x * 256 + threadIdx.x; idx < TOTAL; idx += LOSS_BLOCKS * 256) {
        int b = idx >> 14;
        float c = dc_all[idx];
        float t = dt_all[idx];
        float g = dg_all[idx];
        float d1, d2;
        if (num < 1) {
            d1 = c - g;
            d2 = t - g;
        } else {
            float ec = fabsf(g - c);
            float et = fabsf(g - t);
            float comb_c = w * c + (1.0f - w) * g;
            float comb_t = w * t + (1.0f - w) * g;
            float sup_c = (ec >= thr[b]) ? comb_t : g;      // sup_from_tran
            float sup_t = (et >= thr[B + b]) ? comb_c : g;  // sup_from_conv
            d1 = c - sup_c;
            d2 = t - sup_t;
        }
        acc += (double)(d1 * d1) + (double)(d2 * d2);
    }

    // block-reduce doubles
    __shared__ double s_sum[4];
#pragma unroll
    for (int off = 32; off > 0; off >>= 1) acc += __shfl_down(acc, off, 64);
    int t = threadIdx.x;
    if ((t & 63) == 0) s_sum[t >> 6] = acc;
    __syncthreads();
    if (t == 0) part[blockIdx.x] = s_sum[0] + s_sum[1] + s_sum[2] + s_sum[3];
}

// -------------------- K4: final reduce of 1024 doubles -> f32 scalar ------
__global__ __launch_bounds__(256) void reduce_kernel(const double* __restrict__ part,
                                                     float* __restrict__ out) {
    int t = threadIdx.x;
    double acc = part[t] + part[t + 256] + part[t + 512] + part[t + 768];
#pragma unroll
    for (int off = 32; off > 0; off >>= 1) acc += __shfl_down(acc, off, 64);
    __shared__ double s_sum[4];
    if ((t & 63) == 0) s_sum[t >> 6] = acc;
    __syncthreads();
    if (t == 0) out[0] = (float)(s_sum[0] + s_sum[1] + s_sum[2] + s_sum[3]);
}

extern "C" void kernel_launch(void* const* d_in, const int* in_sizes, int n_in,
                              void* d_out, int out_size, void* d_ws, size_t ws_size,
                              hipStream_t stream) {
    const float* dmap_conv = (const float*)d_in[0];
    const float* dmap_tran = (const float*)d_in[1];
    const float* gt        = (const float*)d_in[2];
    const int*   process   = (const int*)d_in[3];
    float* out = (float*)d_out;

    // workspace layout: dg [TOTAL f32] | thr [64 f32] | part [LOSS_BLOCKS f64]
    char* ws = (char*)d_ws;
    float*  dg   = (float*)ws;                                  // 2 MB
    float*  thr  = (float*)(ws + (size_t)TOTAL * sizeof(float));// 256 B
    double* part = (double*)(ws + (size_t)TOTAL * sizeof(float) + 256); // 8 KB, 8B-aligned

    pool_kernel<<<TOTAL / 256, 256, 0, stream>>>(gt, dg);
    select_kernel<<<B * 2, 256, 0, stream>>>(dmap_conv, dmap_tran, dg, process, thr);
    loss_kernel<<<LOSS_BLOCKS, 256, 0, stream>>>(dmap_conv, dmap_tran, dg, process, thr, part);
    reduce_kernel<<<1, 256, 0, stream>>>(part, out);
}